// Round 16
// baseline (294.780 us; speedup 1.0000x reference)
//
#include <hip/hip_runtime.h>
#include <hip/hip_bf16.h>
#include <cstddef>

#define NNODES 100000
#define NEDGES 1600000
#define CIN 128
#define HID 256
#define ACT 20
#define NGRAPH (NNODES / ACT)
#define BSHIFT 8
#define NB ((NNODES + 255) >> 8)     // 391 buckets of 256 nodes
#define BIN_WGS 1280
#define PER_WG (NEDGES / BIN_WGS)    // 1250
#define CAP 8192                     // bucket window capacity (mean fill 4096)
// cvt id space folded into bin_k's extra blocks:
//   [0,16384) wt0 | [16384,49152) wt1 | [49152,114688) wt2
//   [114688, 114688+1.6M): x -> bf16 (8 elems/item) into xbf (= h0 buffer)
#define XCVT_BASE 114688
#define XCVT_ITEMS 1600000
#define CVT_ITEMS (XCVT_BASE + XCVT_ITEMS)
#define CVT_WGS ((CVT_ITEMS + 255) / 256)

typedef __attribute__((ext_vector_type(8))) short short8;
typedef __attribute__((ext_vector_type(4))) float f32x4;
typedef __attribute__((ext_vector_type(2))) float f32x2;
typedef __attribute__((ext_vector_type(4))) unsigned u32x4;

__device__ __forceinline__ unsigned short f2b(float f) {
    unsigned u = __float_as_uint(f);
    u += 0x7FFF + ((u >> 16) & 1);          // round-to-nearest-even
    return (unsigned short)(u >> 16);
}
__device__ __forceinline__ f32x2 bf2up(unsigned u) {
    f32x2 r;
    r.x = __uint_as_float(u << 16);
    r.y = __uint_as_float(u & 0xffff0000u);
    return r;
}

// ------------- bucketed CSR build + weight/x cvt (blocks >= BIN_WGS) ---------
// r16: BIN_WGS 512 -> 1280 (PER_WG 1250): 2.5x block-level parallelism for
// the sort phase; per-block LDS 31 -> 16 KB.

__global__ __launch_bounds__(256) void bin_k(const int* __restrict__ ei,
                                             int* __restrict__ bfill,
                                             unsigned* __restrict__ entries,
                                             const float* __restrict__ conv_w,
                                             const float* __restrict__ lin1_w,
                                             const float* __restrict__ lin2_w,
                                             const float* __restrict__ x,
                                             unsigned short* __restrict__ wt0,
                                             unsigned short* __restrict__ wt1,
                                             unsigned short* __restrict__ wt2,
                                             unsigned short* __restrict__ xbf) {
    __shared__ int cnt[NB], lofs[NB], base[NB], cur[NB];
    __shared__ unsigned lbuf[PER_WG];
    __shared__ int gdst[PER_WG];
    __shared__ int wsum[4];
    if (blockIdx.x >= BIN_WGS) {          // folded conversion blocks
        int id = (blockIdx.x - BIN_WGS) * 256 + threadIdx.x;
        if (id < 16384) {
            int k = id >> 7, n = id & 127;
            wt0[n * 128 + k] = f2b(conv_w[k * 128 + n]);
        } else if (id < 16384 + 32768) {
            int i = id - 16384;
            wt1[i] = f2b(lin1_w[i]);
        } else if (id < 16384 + 32768 + 65536) {
            int i = id - 49152;
            wt2[i] = f2b(lin2_w[i]);
        } else if (id < CVT_ITEMS) {      // x -> bf16 (8 elems per item)
            size_t b8 = (size_t)(id - XCVT_BASE) * 8;
            const float4* xp = reinterpret_cast<const float4*>(x + b8);
            float4 f0 = xp[0], f1 = xp[1];
            short8 o;
            o[0] = (short)f2b(f0.x); o[1] = (short)f2b(f0.y);
            o[2] = (short)f2b(f0.z); o[3] = (short)f2b(f0.w);
            o[4] = (short)f2b(f1.x); o[5] = (short)f2b(f1.y);
            o[6] = (short)f2b(f1.z); o[7] = (short)f2b(f1.w);
            *reinterpret_cast<short8*>(xbf + b8) = o;
        }
        return;
    }
    const int t = threadIdx.x;
    for (int i = t; i < NB; i += 256) { cnt[i] = 0; cur[i] = 0; }
    __syncthreads();
    const int s = blockIdx.x * PER_WG;
    const int e = s + PER_WG;
    for (int i = s + t; i < e; i += 256)
        atomicAdd(&cnt[ei[NEDGES + i] >> BSHIFT], 1);
    __syncthreads();
    int c0 = (2 * t < NB) ? cnt[2 * t] : 0;
    int c1 = (2 * t + 1 < NB) ? cnt[2 * t + 1] : 0;
    int v = c0 + c1;
    int lane = t & 63, wid = t >> 6;
    int inc = v;
#pragma unroll
    for (int o = 1; o < 64; o <<= 1) {
        int tv = __shfl_up(inc, o, 64);
        if (lane >= o) inc += tv;
    }
    if (lane == 63) wsum[wid] = inc;
    __syncthreads();
    int woff = 0;
#pragma unroll
    for (int w = 0; w < 4; ++w) woff += (w < wid) ? wsum[w] : 0;
    int excl = inc + woff - v;
    if (2 * t < NB) lofs[2 * t] = excl;
    if (2 * t + 1 < NB) lofs[2 * t + 1] = excl + c0;
    __syncthreads();
    for (int b = t; b < NB; b += 256)
        base[b] = cnt[b] ? atomicAdd(&bfill[b], cnt[b]) : 0;
    __syncthreads();
    for (int i = s + t; i < e; i += 256) {
        int src = ei[i], dst = ei[NEDGES + i];
        int b = dst >> BSHIFT;
        int r = atomicAdd(&cur[b], 1);
        int slot = lofs[b] + r;
        lbuf[slot] = ((unsigned)src << 8) | (unsigned)(dst & 255);
        int g = base[b] + r;
        gdst[slot] = (g < CAP) ? (int)((size_t)b * CAP + g) : -1;
    }
    __syncthreads();
    for (int i = t; i < PER_WG; i += 256) {
        int g = gdst[i];
        if (g >= 0) entries[g] = lbuf[i];
    }
}

// bucket_build v3: 512 threads/block (halves per-thread atomic chains);
// scan on threads <256 with block-uniform barriers. csr staged in LDS,
// written out as coalesced int4 sweeps.

__global__ __launch_bounds__(512) void bucket_build_k(
    const unsigned* __restrict__ entries, const int* __restrict__ bfill,
    int2* __restrict__ rowptr2, int* __restrict__ csr, float* __restrict__ dinv) {
    const int b = blockIdx.x;
    const int count = min(bfill[b], CAP);
    const int node0 = b << BSHIFT;
    const int nn = min(256, NNODES - node0);
    const size_t gbase = (size_t)b * CAP;
    __shared__ int cnt[256], off[256], cur[256];
    __shared__ int wsum[4];
    __shared__ int sbuf[CAP];          // 32 KB staging for sorted csr run
    const int t = threadIdx.x;
    if (t < 256) { cnt[t] = 0; cur[t] = 0; }
    __syncthreads();
    for (int i = t; i < count; i += 512)
        atomicAdd(&cnt[entries[gbase + i] & 255], 1);
    __syncthreads();
    const int lane = t & 63, wid = t >> 6;
    int v = (t < 256) ? cnt[t] : 0;
    int inc = v;
#pragma unroll
    for (int o = 1; o < 64; o <<= 1) {
        int tv = __shfl_up(inc, o, 64);
        if (lane >= o) inc += tv;
    }
    if (t < 256 && lane == 63) wsum[wid] = inc;
    __syncthreads();
    int woff = 0;
#pragma unroll
    for (int w = 0; w < 4; ++w) woff += (w < wid) ? wsum[w] : 0;
    int excl = inc + woff - v;
    if (t < 256) off[t] = excl;
    if (t < nn) {
        rowptr2[node0 + t] = make_int2((int)gbase + excl, (int)gbase + excl + v);
        dinv[node0 + t] = rsqrtf(1.0f + (float)v);
    }
    __syncthreads();
    for (int i = t; i < count; i += 512) {
        unsigned en = entries[gbase + i];
        int loc = (int)(en & 255);
        int r = atomicAdd(&cur[loc], 1);
        sbuf[off[loc] + r] = (int)(en >> 8);
    }
    __syncthreads();
    const int c4 = count >> 2;
    const int4* sb4 = reinterpret_cast<const int4*>(sbuf);
    int4* cs4 = reinterpret_cast<int4*>(csr + gbase);
    for (int i = t; i < c4; i += 512) cs4[i] = sb4[i];
    for (int i = (c4 << 2) + t; i < count; i += 512) csr[gbase + i] = sbuf[i];
}

// ---------------- mgemm0 v2: A staged via global_load_lds -------------------

__global__ __launch_bounds__(256, 2) void mgemm0_k(
    const unsigned short* __restrict__ Abf, const unsigned short* __restrict__ B,
    const float* __restrict__ dinv, unsigned short* __restrict__ Cout, int M)
{
    __shared__ unsigned short xbs[128 * 128];   // 32 KB, chunk-XOR swizzled
    const int tid = threadIdx.x;
    const int wid = tid >> 6;
    const int lane = tid & 63;
    const int quad = lane >> 4;
    const int l16 = lane & 15;
    const int bm = blockIdx.x * 128 + (wid >> 1) * 64;
    const int bn = (wid & 1) * 64;
    const int wave = wid;

    // stage A tile: 8 rounds x 256 thr x 16B = 32 KB (linear LDS dest,
    // pre-swizzled global source; rows >= M read garbage, outputs guarded)
    {
        typedef __attribute__((address_space(1))) const unsigned short* gp_t;
        typedef __attribute__((address_space(3))) unsigned short* lp_t;
#pragma unroll
        for (int p = 0; p < 8; ++p) {
            const int L = p * 256 + tid;
            const int r = L >> 4, sc = L & 15;
            const int c = (sc & 8) | ((sc ^ r) & 7);
            const unsigned short* gsrc = Abf + (size_t)(blockIdx.x * 128 + r) * 128 + c * 8;
            __builtin_amdgcn_global_load_lds((gp_t)gsrc,
                (lp_t)(xbs + (size_t)(p * 256 + wave * 64) * 8), 16, 0, 0);
        }
    }

    const unsigned short* pb[4];
#pragma unroll
    for (int t = 0; t < 4; ++t) {
        int n = bn + t * 16 + l16;
        pb[t] = B + (size_t)n * 128 + quad * 8;
    }

    f32x4 acc[4][4];
#pragma unroll
    for (int i = 0; i < 4; ++i)
#pragma unroll
        for (int j = 0; j < 4; ++j) {
            f32x4 z = {0.f, 0.f, 0.f, 0.f};
            acc[i][j] = z;
        }

    __syncthreads();   // drains vmcnt -> tile ready

    short8 af[2][4], bf[2][4];
#pragma unroll
    for (int t = 0; t < 4; ++t) {
        const int row = (wid >> 1) * 64 + t * 16 + l16;
        const int c = quad;                       // kt=0
        const int pos = (c & 8) | ((c ^ row) & 7);
        af[0][t] = *reinterpret_cast<const short8*>(&xbs[row * 128 + pos * 8]);
        bf[0][t] = *reinterpret_cast<const short8*>(pb[t]);
    }

#pragma unroll
    for (int kt = 0; kt < 4; ++kt) {
        const int cur = kt & 1, nxt = cur ^ 1;
        if (kt < 3) {
#pragma unroll
            for (int t = 0; t < 4; ++t) {
                const int row = (wid >> 1) * 64 + t * 16 + l16;
                const int c = (kt + 1) * 4 + quad;
                const int pos = (c & 8) | ((c ^ row) & 7);
                af[nxt][t] = *reinterpret_cast<const short8*>(&xbs[row * 128 + pos * 8]);
                bf[nxt][t] = *reinterpret_cast<const short8*>(pb[t] + (kt + 1) * 32);
            }
        }
#pragma unroll
        for (int i = 0; i < 4; ++i)
#pragma unroll
            for (int j = 0; j < 4; ++j)
                acc[i][j] = __builtin_amdgcn_mfma_f32_16x16x32_bf16(af[cur][i], bf[cur][j], acc[i][j], 0, 0, 0);
    }

#pragma unroll
    for (int i = 0; i < 4; ++i)
#pragma unroll
        for (int r = 0; r < 4; ++r) {
            int row = bm + i * 16 + quad * 4 + r;
            if (row >= M) continue;
            float dv = dinv[row];
#pragma unroll
            for (int j = 0; j < 4; ++j) {
                int col = bn + j * 16 + l16;
                Cout[(size_t)row * 128 + col] = f2b(acc[i][j][r] * dv);
            }
        }
}

// ---------------- gather v12 (proven best, R8): no NT --------------------

__global__ __launch_bounds__(256) void gather_k(
    const int2* __restrict__ rowptr2, const int* __restrict__ csr,
    const unsigned short* __restrict__ xws, const float* __restrict__ dinv,
    const float* __restrict__ x, const float* __restrict__ conv_b,
    unsigned short* __restrict__ h0)
{
    const int node = blockIdx.x * 4 + (threadIdx.x >> 6);
    if (node >= NNODES) return;
    const int lane = threadIdx.x & 63;
    const int sub = lane >> 4;
    const int c16 = lane & 15;

    const int2 se = rowptr2[node];
    const int start = se.x, end = se.y;

    f32x2 a[4];
    if (sub == 0) {          // self-loop contribution, counted once
        u32x4 v = *reinterpret_cast<const u32x4*>(xws + (size_t)node * CIN + c16 * 8);
        a[0] = bf2up(v.x); a[1] = bf2up(v.y); a[2] = bf2up(v.z); a[3] = bf2up(v.w);
    } else {
        f32x2 z = {0.f, 0.f};
        a[0] = z; a[1] = z; a[2] = z; a[3] = z;
    }

    const int es = start & ~3;          // 16B-align csr windows
    for (int q = es; q < end; q += 16) {
        const int b0 = q + sub * 4;     // this subgroup's 4 consecutive edges
        const u32x4 ic = *reinterpret_cast<const u32x4*>(csr + b0);
        u32x4 r[4];
        bool val[4];
#pragma unroll
        for (int j = 0; j < 4; ++j) {
            const int e = b0 + j;
            const bool ok = (e >= start) & (e < end);
            const int idx = ok ? (int)ic[j] : node;
            r[j] = *reinterpret_cast<const u32x4*>(xws + (size_t)idx * CIN + c16 * 8);
            val[j] = ok;
        }
#pragma unroll
        for (int j = 0; j < 4; ++j)
            if (val[j]) {
                a[0] += bf2up(r[j].x); a[1] += bf2up(r[j].y);
                a[2] += bf2up(r[j].z); a[3] += bf2up(r[j].w);
            }
    }

#pragma unroll
    for (int k = 0; k < 4; ++k) {
        a[k].x += __shfl_xor(a[k].x, 16, 64);
        a[k].y += __shfl_xor(a[k].y, 16, 64);
        a[k].x += __shfl_xor(a[k].x, 32, 64);
        a[k].y += __shfl_xor(a[k].y, 32, 64);
    }

    if (sub == 0) {
        const float dv = dinv[node];
        const float4 b0v = *reinterpret_cast<const float4*>(conv_b + c16 * 8);
        const float4 b1v = *reinterpret_cast<const float4*>(conv_b + c16 * 8 + 4);
        const float4 x0 = *reinterpret_cast<const float4*>(x + (size_t)node * CIN + c16 * 8);
        const float4 x1 = *reinterpret_cast<const float4*>(x + (size_t)node * CIN + c16 * 8 + 4);
        float o[8];
        o[0] = fmaxf(a[0].x * dv + b0v.x, 0.f) + x0.x;
        o[1] = fmaxf(a[0].y * dv + b0v.y, 0.f) + x0.y;
        o[2] = fmaxf(a[1].x * dv + b0v.z, 0.f) + x0.z;
        o[3] = fmaxf(a[1].y * dv + b0v.w, 0.f) + x0.w;
        o[4] = fmaxf(a[2].x * dv + b1v.x, 0.f) + x1.x;
        o[5] = fmaxf(a[2].y * dv + b1v.y, 0.f) + x1.y;
        o[6] = fmaxf(a[3].x * dv + b1v.z, 0.f) + x1.z;
        o[7] = fmaxf(a[3].y * dv + b1v.w, 0.f) + x1.w;
        u32x4 pk;
        pk.x = (unsigned)f2b(o[0]) | ((unsigned)f2b(o[1]) << 16);
        pk.y = (unsigned)f2b(o[2]) | ((unsigned)f2b(o[3]) << 16);
        pk.z = (unsigned)f2b(o[4]) | ((unsigned)f2b(o[5]) << 16);
        pk.w = (unsigned)f2b(o[6]) | ((unsigned)f2b(o[7]) << 16);
        *reinterpret_cast<u32x4*>(h0 + (size_t)node * CIN + c16 * 8) = pk;
    }
}

// ---------------- fused MLP v7: h0 tile staged via global_load_lds ----------

__global__ __launch_bounds__(256, 2) void fmlp_k(
    const unsigned short* __restrict__ h0, const unsigned short* __restrict__ w1,
    const float* __restrict__ b1, const unsigned short* __restrict__ w2,
    const float* __restrict__ b2, const float* __restrict__ w3,
    float* __restrict__ rowsum, int M)
{
    __shared__ unsigned short h1s[64 * 256];   // 32 KB, xor-swizzled
    __shared__ unsigned short h0s[64 * 128];   // 16 KB, chunk-XOR swizzled
    const int tid = threadIdx.x;
    const int wave = tid >> 6;
    const int lane = tid & 63;
    const int quad = lane >> 4;
    const int l16 = lane & 15;
    const int bm = blockIdx.x * 64;
    const int nc0 = wave * 64;

    // ---- stage h0 tile: 4 rounds x 256 threads x 16B = 16KB ----
    {
        typedef __attribute__((address_space(1))) const unsigned short* gp_t;
        typedef __attribute__((address_space(3))) unsigned short* lp_t;
#pragma unroll
        for (int p = 0; p < 4; ++p) {
            const int L = p * 256 + tid;
            const int r = L >> 4, sc = L & 15;
            const int c = (sc & 8) | ((sc ^ r) & 7);
            const unsigned short* gsrc = h0 + (size_t)(bm + r) * 128 + c * 8;
            __builtin_amdgcn_global_load_lds((gp_t)gsrc,
                (lp_t)(h0s + (size_t)(p * 256 + wave * 64) * 8), 16, 0, 0);
        }
    }

    f32x4 acc[4][4];
#pragma unroll
    for (int i = 0; i < 4; ++i)
#pragma unroll
        for (int j = 0; j < 4; ++j) {
            f32x4 z = {0.f, 0.f, 0.f, 0.f};
            acc[i][j] = z;
        }

    __syncthreads();   // compiler drains vmcnt before barrier -> tile ready

    // ---- phase 1: h1 = relu(h0 @ W1^T + b1), K=128; A from LDS ----
    {
        const unsigned short* pb[4];
#pragma unroll
        for (int t = 0; t < 4; ++t) {
            int n = nc0 + t * 16 + l16;
            pb[t] = w1 + (size_t)n * 128 + quad * 8;
        }
        short8 af[2][4], bf[2][4];
#pragma unroll
        for (int t = 0; t < 4; ++t) {
            const int row = t * 16 + l16;
            const int c = quad;                       // kt=0
            const int pos = (c & 8) | ((c ^ row) & 7);
            af[0][t] = *reinterpret_cast<const short8*>(&h0s[row * 128 + pos * 8]);
            bf[0][t] = *reinterpret_cast<const short8*>(pb[t]);
        }
#pragma unroll
        for (int kt = 0; kt < 4; ++kt) {
            const int cur = kt & 1, nxt = cur ^ 1;
            if (kt < 3) {
#pragma unroll
                for (int t = 0; t < 4; ++t) {
                    const int row = t * 16 + l16;
                    const int c = (kt + 1) * 4 + quad;
                    const int pos = (c & 8) | ((c ^ row) & 7);
                    af[nxt][t] = *reinterpret_cast<const short8*>(&h0s[row * 128 + pos * 8]);
                    bf[nxt][t] = *reinterpret_cast<const short8*>(pb[t] + (kt + 1) * 32);
                }
            }
#pragma unroll
            for (int i = 0; i < 4; ++i)
#pragma unroll
                for (int j = 0; j < 4; ++j)
                    acc[i][j] = __builtin_amdgcn_mfma_f32_16x16x32_bf16(af[cur][i], bf[cur][j], acc[i][j], 0, 0, 0);
        }
        // relu+bias -> swizzled LDS: (row,col) at row*256 + (((col>>3)^(row&7))<<3 | (col&7))
#pragma unroll
        for (int nt = 0; nt < 4; ++nt) {
            int col = nc0 + nt * 16 + l16;
            float bv = b1[col];
            int chunk = col >> 3, rem = col & 7;
#pragma unroll
            for (int mt = 0; mt < 4; ++mt)
#pragma unroll
                for (int r = 0; r < 4; ++r) {
                    int row = mt * 16 + quad * 4 + r;
                    h1s[row * 256 + (((chunk ^ (row & 7)) << 3) | rem)] =
                        f2b(fmaxf(acc[mt][nt][r] + bv, 0.f));
                }
        }
    }
    __syncthreads();

    // ---- phase 2: h2 = relu(h1s @ W2^T + b2), K=256, ring-3 both streams ----
#pragma unroll
    for (int i = 0; i < 4; ++i)
#pragma unroll
        for (int j = 0; j < 4; ++j) {
            f32x4 z = {0.f, 0.f, 0.f, 0.f};
            acc[i][j] = z;
        }
    {
        const unsigned short* pb[4];
#pragma unroll
        for (int t = 0; t < 4; ++t) {
            int n = nc0 + t * 16 + l16;
            pb[t] = w2 + (size_t)n * 256 + quad * 8;
        }
        short8 af[3][4], bf[3][4];
#pragma unroll
        for (int t = 0; t < 4; ++t) {
            int row = t * 16 + l16;
            af[0][t] = *reinterpret_cast<const short8*>(
                &h1s[row * 256 + ((quad ^ (row & 7)) << 3)]);
            af[1][t] = *reinterpret_cast<const short8*>(
                &h1s[row * 256 + (((4 + quad) ^ (row & 7)) << 3)]);
            bf[0][t] = *reinterpret_cast<const short8*>(pb[t]);
            bf[1][t] = *reinterpret_cast<const short8*>(pb[t] + 32);
        }
#pragma unroll
        for (int kt = 0; kt < 8; ++kt) {
            const int cu = kt % 3, nx = (kt + 2) % 3;
            if (kt + 2 < 8) {
                const int c2 = (kt + 2) * 4 + quad;
#pragma unroll
                for (int t = 0; t < 4; ++t) {
                    int row = t * 16 + l16;
                    af[nx][t] = *reinterpret_cast<const short8*>(
                        &h1s[row * 256 + ((c2 ^ (row & 7)) << 3)]);
                    bf[nx][t] = *reinterpret_cast<const short8*>(pb[t] + (kt + 2) * 32);
                }
            }
#pragma unroll
            for (int i = 0; i < 4; ++i)
#pragma unroll
                for (int j = 0; j < 4; ++j)
                    acc[i][j] = __builtin_amdgcn_mfma_f32_16x16x32_bf16(af[cu][i], bf[cu][j], acc[i][j], 0, 0, 0);
        }
    }

    // ---- fused epilogue: partial w3-dot over this wave's 64 cols ----
    float part[4][4];
#pragma unroll
    for (int mt = 0; mt < 4; ++mt)
#pragma unroll
        for (int r = 0; r < 4; ++r) part[mt][r] = 0.f;
#pragma unroll
    for (int nt = 0; nt < 4; ++nt) {
        int col = nc0 + nt * 16 + l16;
        float bs = b2[col];
        float wv3 = w3[col];
#pragma unroll
        for (int mt = 0; mt < 4; ++mt)
#pragma unroll
            for (int r = 0; r < 4; ++r)
                part[mt][r] += fmaxf(acc[mt][nt][r] + bs, 0.f) * wv3;
    }
#pragma unroll
    for (int mt = 0; mt < 4; ++mt)
#pragma unroll
        for (int r = 0; r < 4; ++r) {
            float v = part[mt][r];
            v += __shfl_xor(v, 1, 64);
            v += __shfl_xor(v, 2, 64);
            v += __shfl_xor(v, 4, 64);
            v += __shfl_xor(v, 8, 64);
            part[mt][r] = v;
        }
    if (l16 == 0) {
#pragma unroll
        for (int mt = 0; mt < 4; ++mt)
#pragma unroll
            for (int r = 0; r < 4; ++r) {
                int row = bm + mt * 16 + quad * 4 + r;
                if (row < M) rowsum[(size_t)row * 4 + wave] = part[mt][r];
            }
    }
}

// ---------------- final: out[g] = b3 + sum of 80 rowsum slots ----------------

__global__ __launch_bounds__(256) void final_k(
    const float* __restrict__ rowsum, const float* __restrict__ b3,
    float* __restrict__ out)
{
    int g = blockIdx.x * 256 + threadIdx.x;
    if (g >= NGRAPH) return;
    const float4* p = reinterpret_cast<const float4*>(rowsum + (size_t)g * 80);
    float s = 0.f;
#pragma unroll
    for (int i = 0; i < 20; ++i) {
        float4 v = p[i];
        s += (v.x + v.y) + (v.z + v.w);
    }
    out[g] = s + b3[0];
}

// ---------------- launch ----------------

extern "C" void kernel_launch(void* const* d_in, const int* in_sizes, int n_in,
                              void* d_out, int out_size, void* d_ws, size_t ws_size,
                              hipStream_t stream)
{
    const float* x      = (const float*)d_in[0];
    const int*   ei     = (const int*)  d_in[1];
    const float* conv_w = (const float*)d_in[2];
    const float* conv_b = (const float*)d_in[3];
    const float* lin1_w = (const float*)d_in[4];
    const float* lin1_b = (const float*)d_in[5];
    const float* lin2_w = (const float*)d_in[6];
    const float* lin2_b = (const float*)d_in[7];
    const float* lin3_w = (const float*)d_in[8];
    const float* lin3_b = (const float*)d_in[9];
    float* out = (float*)d_out;

    // Workspace (~80 MB):
    //   xws bf16 [(N+8)*128] | h0 bf16 [N*128] (doubles as xbf before gather)
    //   entries | csr | rowptr2 int2 [N] | dinv [N] | bfill [NB]
    //   wt0/wt1/wt2 | rowsum [100096*4]
    unsigned short* xws     = (unsigned short*)d_ws;
    unsigned short* h0      = xws + (size_t)(NNODES + 8) * 128;   // aka xbf
    unsigned*       entries = (unsigned*)(h0 + (size_t)NNODES * 128);
    int*            csr     = (int*)(entries + (size_t)NB * CAP);
    int2*           rowptr2 = (int2*)(csr + (size_t)NB * CAP);
    float*          dinv    = (float*)(rowptr2 + NNODES);
    int*            bfill   = (int*)(dinv + NNODES);
    unsigned short* wt0     = (unsigned short*)(bfill + NB + 8);
    unsigned short* wt1     = wt0 + 16384;
    unsigned short* wt2     = wt1 + 32768;
    float*          rowsum  = (float*)(wt2 + 65536);

    // CSR build + folded weight conversions + x->bf16 (into h0 buffer)
    hipMemsetAsync(bfill, 0, NB * sizeof(int), stream);
    bin_k<<<BIN_WGS + CVT_WGS, 256, 0, stream>>>(ei, bfill, entries,
                                                 conv_w, lin1_w, lin2_w, x,
                                                 wt0, wt1, wt2, h0);
    bucket_build_k<<<NB, 512, 0, stream>>>(entries, bfill, rowptr2, csr, dinv);

    // gemm0: xws = (xbf @ conv_w) * dinv[row]; A staged via global_load_lds
    mgemm0_k<<<(NNODES + 127) / 128, 256, 0, stream>>>(h0, wt0, dinv, xws, NNODES);

    // gather + conv epilogue + residual (fp32 x) -> h0 row-major (overwrites xbf)
    gather_k<<<(NNODES + 3) / 4, 256, 0, stream>>>(rowptr2, csr, xws, dinv, x, conv_b, h0);

    // fused MLP: stage h0 -> gemm1 -> LDS -> gemm2 -> w3-dot -> rowsum
    fmlp_k<<<(NNODES + 63) / 64, 256, 0, stream>>>(h0, wt1, lin1_b, wt2, lin2_b, lin3_w,
                                                   rowsum, NNODES);

    // out[g] = b3 + sum of this graph's 80 rowsum slots
    final_k<<<(NGRAPH + 255) / 256, 256, 0, stream>>>(rowsum, lin3_b, out);
}

// Round 17
// 275.522 us; speedup vs baseline: 1.0699x; 1.0699x over previous
//
#include <hip/hip_runtime.h>
#include <hip/hip_bf16.h>
#include <cstddef>

#define NNODES 100000
#define NEDGES 1600000
#define CIN 128
#define HID 256
#define ACT 20
#define NGRAPH (NNODES / ACT)
#define BSHIFT 8
#define NB ((NNODES + 255) >> 8)     // 391 buckets of 256 nodes
#define BIN_WGS 512
#define PER_WG (NEDGES / BIN_WGS)    // 3125
#define CAP 8192                     // bucket window capacity (mean fill 4096)
// cvt id space folded into bin_k's extra blocks:
//   [0,16384) wt0 | [16384,49152) wt1 | [49152,114688) wt2
//   [114688, 114688+1.6M): x -> bf16 (8 elems/item) into xbf (= h0 buffer)
#define XCVT_BASE 114688
#define XCVT_ITEMS 1600000
#define CVT_ITEMS (XCVT_BASE + XCVT_ITEMS)
#define CVT_WGS ((CVT_ITEMS + 255) / 256)

typedef __attribute__((ext_vector_type(8))) short short8;
typedef __attribute__((ext_vector_type(4))) float f32x4;
typedef __attribute__((ext_vector_type(2))) float f32x2;
typedef __attribute__((ext_vector_type(4))) unsigned u32x4;

__device__ __forceinline__ unsigned short f2b(float f) {
    unsigned u = __float_as_uint(f);
    u += 0x7FFF + ((u >> 16) & 1);          // round-to-nearest-even
    return (unsigned short)(u >> 16);
}
__device__ __forceinline__ f32x2 bf2up(unsigned u) {
    f32x2 r;
    r.x = __uint_as_float(u << 16);
    r.y = __uint_as_float(u & 0xffff0000u);
    return r;
}

// ------------- bucketed CSR build + weight/x cvt (blocks >= BIN_WGS) ---------

__global__ __launch_bounds__(256) void bin_k(const int* __restrict__ ei,
                                             int* __restrict__ bfill,
                                             unsigned* __restrict__ entries,
                                             const float* __restrict__ conv_w,
                                             const float* __restrict__ lin1_w,
                                             const float* __restrict__ lin2_w,
                                             const float* __restrict__ x,
                                             unsigned short* __restrict__ wt0,
                                             unsigned short* __restrict__ wt1,
                                             unsigned short* __restrict__ wt2,
                                             unsigned short* __restrict__ xbf) {
    __shared__ int cnt[NB], lofs[NB], base[NB], cur[NB];
    __shared__ unsigned lbuf[PER_WG];
    __shared__ int gdst[PER_WG];
    __shared__ int wsum[4];
    if (blockIdx.x >= BIN_WGS) {          // folded conversion blocks
        int id = (blockIdx.x - BIN_WGS) * 256 + threadIdx.x;
        if (id < 16384) {
            int k = id >> 7, n = id & 127;
            wt0[n * 128 + k] = f2b(conv_w[k * 128 + n]);
        } else if (id < 16384 + 32768) {
            int i = id - 16384;
            wt1[i] = f2b(lin1_w[i]);
        } else if (id < 16384 + 32768 + 65536) {
            int i = id - 49152;
            wt2[i] = f2b(lin2_w[i]);
        } else if (id < CVT_ITEMS) {      // x -> bf16 (8 elems per item)
            size_t b8 = (size_t)(id - XCVT_BASE) * 8;
            const float4* xp = reinterpret_cast<const float4*>(x + b8);
            float4 f0 = xp[0], f1 = xp[1];
            short8 o;
            o[0] = (short)f2b(f0.x); o[1] = (short)f2b(f0.y);
            o[2] = (short)f2b(f0.z); o[3] = (short)f2b(f0.w);
            o[4] = (short)f2b(f1.x); o[5] = (short)f2b(f1.y);
            o[6] = (short)f2b(f1.z); o[7] = (short)f2b(f1.w);
            *reinterpret_cast<short8*>(xbf + b8) = o;
        }
        return;
    }
    const int t = threadIdx.x;
    for (int i = t; i < NB; i += 256) { cnt[i] = 0; cur[i] = 0; }
    __syncthreads();
    const int s = blockIdx.x * PER_WG;
    const int e = s + PER_WG;
    for (int i = s + t; i < e; i += 256)
        atomicAdd(&cnt[ei[NEDGES + i] >> BSHIFT], 1);
    __syncthreads();
    int c0 = (2 * t < NB) ? cnt[2 * t] : 0;
    int c1 = (2 * t + 1 < NB) ? cnt[2 * t + 1] : 0;
    int v = c0 + c1;
    int lane = t & 63, wid = t >> 6;
    int inc = v;
#pragma unroll
    for (int o = 1; o < 64; o <<= 1) {
        int tv = __shfl_up(inc, o, 64);
        if (lane >= o) inc += tv;
    }
    if (lane == 63) wsum[wid] = inc;
    __syncthreads();
    int woff = 0;
#pragma unroll
    for (int w = 0; w < 4; ++w) woff += (w < wid) ? wsum[w] : 0;
    int excl = inc + woff - v;
    if (2 * t < NB) lofs[2 * t] = excl;
    if (2 * t + 1 < NB) lofs[2 * t + 1] = excl + c0;
    __syncthreads();
    for (int b = t; b < NB; b += 256)
        base[b] = cnt[b] ? atomicAdd(&bfill[b], cnt[b]) : 0;
    __syncthreads();
    for (int i = s + t; i < e; i += 256) {
        int src = ei[i], dst = ei[NEDGES + i];
        int b = dst >> BSHIFT;
        int r = atomicAdd(&cur[b], 1);
        int slot = lofs[b] + r;
        lbuf[slot] = ((unsigned)src << 8) | (unsigned)(dst & 255);
        int g = base[b] + r;
        gdst[slot] = (g < CAP) ? (int)((size_t)b * CAP + g) : -1;
    }
    __syncthreads();
    for (int i = t; i < PER_WG; i += 256) {
        int g = gdst[i];
        if (g >= 0) entries[g] = lbuf[i];
    }
}

// bucket_build v2: csr staged in LDS, written out as coalesced int4 sweeps.

__global__ __launch_bounds__(256) void bucket_build_k(
    const unsigned* __restrict__ entries, const int* __restrict__ bfill,
    int2* __restrict__ rowptr2, int* __restrict__ csr, float* __restrict__ dinv) {
    const int b = blockIdx.x;
    const int count = min(bfill[b], CAP);
    const int node0 = b << BSHIFT;
    const int nn = min(256, NNODES - node0);
    const size_t gbase = (size_t)b * CAP;
    __shared__ int cnt[256], off[256], cur[256];
    __shared__ int wsum[4];
    __shared__ int sbuf[CAP];          // 32 KB staging for sorted csr run
    const int t = threadIdx.x;
    cnt[t] = 0; cur[t] = 0;
    __syncthreads();
    for (int i = t; i < count; i += 256)
        atomicAdd(&cnt[entries[gbase + i] & 255], 1);
    __syncthreads();
    int lane = t & 63, wid = t >> 6;
    int v = cnt[t];
    int inc = v;
#pragma unroll
    for (int o = 1; o < 64; o <<= 1) {
        int tv = __shfl_up(inc, o, 64);
        if (lane >= o) inc += tv;
    }
    if (lane == 63) wsum[wid] = inc;
    __syncthreads();
    int woff = 0;
#pragma unroll
    for (int w = 0; w < 4; ++w) woff += (w < wid) ? wsum[w] : 0;
    int excl = inc + woff - v;
    off[t] = excl;
    if (t < nn) {
        rowptr2[node0 + t] = make_int2((int)gbase + excl, (int)gbase + excl + v);
        dinv[node0 + t] = rsqrtf(1.0f + (float)v);
    }
    __syncthreads();
    for (int i = t; i < count; i += 256) {
        unsigned en = entries[gbase + i];
        int loc = (int)(en & 255);
        int r = atomicAdd(&cur[loc], 1);
        sbuf[off[loc] + r] = (int)(en >> 8);
    }
    __syncthreads();
    const int c4 = count >> 2;
    const int4* sb4 = reinterpret_cast<const int4*>(sbuf);
    int4* cs4 = reinterpret_cast<int4*>(csr + gbase);
    for (int i = t; i < c4; i += 256) cs4[i] = sb4[i];
    for (int i = (c4 << 2) + t; i < count; i += 256) csr[gbase + i] = sbuf[i];
}

// ---------------- mgemm0 v2: A staged via global_load_lds -------------------

__global__ __launch_bounds__(256, 2) void mgemm0_k(
    const unsigned short* __restrict__ Abf, const unsigned short* __restrict__ B,
    const float* __restrict__ dinv, unsigned short* __restrict__ Cout, int M)
{
    __shared__ unsigned short xbs[128 * 128];   // 32 KB, chunk-XOR swizzled
    const int tid = threadIdx.x;
    const int wid = tid >> 6;
    const int lane = tid & 63;
    const int quad = lane >> 4;
    const int l16 = lane & 15;
    const int bm = blockIdx.x * 128 + (wid >> 1) * 64;
    const int bn = (wid & 1) * 64;
    const int wave = wid;

    // stage A tile: 8 rounds x 256 thr x 16B = 32 KB (linear LDS dest,
    // pre-swizzled global source; rows >= M read garbage, outputs guarded)
    {
        typedef __attribute__((address_space(1))) const unsigned short* gp_t;
        typedef __attribute__((address_space(3))) unsigned short* lp_t;
#pragma unroll
        for (int p = 0; p < 8; ++p) {
            const int L = p * 256 + tid;
            const int r = L >> 4, sc = L & 15;
            const int c = (sc & 8) | ((sc ^ r) & 7);
            const unsigned short* gsrc = Abf + (size_t)(blockIdx.x * 128 + r) * 128 + c * 8;
            __builtin_amdgcn_global_load_lds((gp_t)gsrc,
                (lp_t)(xbs + (size_t)(p * 256 + wave * 64) * 8), 16, 0, 0);
        }
    }

    const unsigned short* pb[4];
#pragma unroll
    for (int t = 0; t < 4; ++t) {
        int n = bn + t * 16 + l16;
        pb[t] = B + (size_t)n * 128 + quad * 8;
    }

    f32x4 acc[4][4];
#pragma unroll
    for (int i = 0; i < 4; ++i)
#pragma unroll
        for (int j = 0; j < 4; ++j) {
            f32x4 z = {0.f, 0.f, 0.f, 0.f};
            acc[i][j] = z;
        }

    __syncthreads();   // drains vmcnt -> tile ready

    short8 af[2][4], bf[2][4];
#pragma unroll
    for (int t = 0; t < 4; ++t) {
        const int row = (wid >> 1) * 64 + t * 16 + l16;
        const int c = quad;                       // kt=0
        const int pos = (c & 8) | ((c ^ row) & 7);
        af[0][t] = *reinterpret_cast<const short8*>(&xbs[row * 128 + pos * 8]);
        bf[0][t] = *reinterpret_cast<const short8*>(pb[t]);
    }

#pragma unroll
    for (int kt = 0; kt < 4; ++kt) {
        const int cur = kt & 1, nxt = cur ^ 1;
        if (kt < 3) {
#pragma unroll
            for (int t = 0; t < 4; ++t) {
                const int row = (wid >> 1) * 64 + t * 16 + l16;
                const int c = (kt + 1) * 4 + quad;
                const int pos = (c & 8) | ((c ^ row) & 7);
                af[nxt][t] = *reinterpret_cast<const short8*>(&xbs[row * 128 + pos * 8]);
                bf[nxt][t] = *reinterpret_cast<const short8*>(pb[t] + (kt + 1) * 32);
            }
        }
#pragma unroll
        for (int i = 0; i < 4; ++i)
#pragma unroll
            for (int j = 0; j < 4; ++j)
                acc[i][j] = __builtin_amdgcn_mfma_f32_16x16x32_bf16(af[cur][i], bf[cur][j], acc[i][j], 0, 0, 0);
    }

#pragma unroll
    for (int i = 0; i < 4; ++i)
#pragma unroll
        for (int r = 0; r < 4; ++r) {
            int row = bm + i * 16 + quad * 4 + r;
            if (row >= M) continue;
            float dv = dinv[row];
#pragma unroll
            for (int j = 0; j < 4; ++j) {
                int col = bn + j * 16 + l16;
                Cout[(size_t)row * 128 + col] = f2b(acc[i][j][r] * dv);
            }
        }
}

// ---------------- gather v12 (proven best, R8): no NT --------------------

__global__ __launch_bounds__(256) void gather_k(
    const int2* __restrict__ rowptr2, const int* __restrict__ csr,
    const unsigned short* __restrict__ xws, const float* __restrict__ dinv,
    const float* __restrict__ x, const float* __restrict__ conv_b,
    unsigned short* __restrict__ h0)
{
    const int node = blockIdx.x * 4 + (threadIdx.x >> 6);
    if (node >= NNODES) return;
    const int lane = threadIdx.x & 63;
    const int sub = lane >> 4;
    const int c16 = lane & 15;

    const int2 se = rowptr2[node];
    const int start = se.x, end = se.y;

    f32x2 a[4];
    if (sub == 0) {          // self-loop contribution, counted once
        u32x4 v = *reinterpret_cast<const u32x4*>(xws + (size_t)node * CIN + c16 * 8);
        a[0] = bf2up(v.x); a[1] = bf2up(v.y); a[2] = bf2up(v.z); a[3] = bf2up(v.w);
    } else {
        f32x2 z = {0.f, 0.f};
        a[0] = z; a[1] = z; a[2] = z; a[3] = z;
    }

    const int es = start & ~3;          // 16B-align csr windows
    for (int q = es; q < end; q += 16) {
        const int b0 = q + sub * 4;     // this subgroup's 4 consecutive edges
        const u32x4 ic = *reinterpret_cast<const u32x4*>(csr + b0);
        u32x4 r[4];
        bool val[4];
#pragma unroll
        for (int j = 0; j < 4; ++j) {
            const int e = b0 + j;
            const bool ok = (e >= start) & (e < end);
            const int idx = ok ? (int)ic[j] : node;
            r[j] = *reinterpret_cast<const u32x4*>(xws + (size_t)idx * CIN + c16 * 8);
            val[j] = ok;
        }
#pragma unroll
        for (int j = 0; j < 4; ++j)
            if (val[j]) {
                a[0] += bf2up(r[j].x); a[1] += bf2up(r[j].y);
                a[2] += bf2up(r[j].z); a[3] += bf2up(r[j].w);
            }
    }

#pragma unroll
    for (int k = 0; k < 4; ++k) {
        a[k].x += __shfl_xor(a[k].x, 16, 64);
        a[k].y += __shfl_xor(a[k].y, 16, 64);
        a[k].x += __shfl_xor(a[k].x, 32, 64);
        a[k].y += __shfl_xor(a[k].y, 32, 64);
    }

    if (sub == 0) {
        const float dv = dinv[node];
        const float4 b0v = *reinterpret_cast<const float4*>(conv_b + c16 * 8);
        const float4 b1v = *reinterpret_cast<const float4*>(conv_b + c16 * 8 + 4);
        const float4 x0 = *reinterpret_cast<const float4*>(x + (size_t)node * CIN + c16 * 8);
        const float4 x1 = *reinterpret_cast<const float4*>(x + (size_t)node * CIN + c16 * 8 + 4);
        float o[8];
        o[0] = fmaxf(a[0].x * dv + b0v.x, 0.f) + x0.x;
        o[1] = fmaxf(a[0].y * dv + b0v.y, 0.f) + x0.y;
        o[2] = fmaxf(a[1].x * dv + b0v.z, 0.f) + x0.z;
        o[3] = fmaxf(a[1].y * dv + b0v.w, 0.f) + x0.w;
        o[4] = fmaxf(a[2].x * dv + b1v.x, 0.f) + x1.x;
        o[5] = fmaxf(a[2].y * dv + b1v.y, 0.f) + x1.y;
        o[6] = fmaxf(a[3].x * dv + b1v.z, 0.f) + x1.z;
        o[7] = fmaxf(a[3].y * dv + b1v.w, 0.f) + x1.w;
        u32x4 pk;
        pk.x = (unsigned)f2b(o[0]) | ((unsigned)f2b(o[1]) << 16);
        pk.y = (unsigned)f2b(o[2]) | ((unsigned)f2b(o[3]) << 16);
        pk.z = (unsigned)f2b(o[4]) | ((unsigned)f2b(o[5]) << 16);
        pk.w = (unsigned)f2b(o[6]) | ((unsigned)f2b(o[7]) << 16);
        *reinterpret_cast<u32x4*>(h0 + (size_t)node * CIN + c16 * 8) = pk;
    }
}

// ---------------- fused MLP v7: h0 tile staged via global_load_lds ----------

__global__ __launch_bounds__(256, 2) void fmlp_k(
    const unsigned short* __restrict__ h0, const unsigned short* __restrict__ w1,
    const float* __restrict__ b1, const unsigned short* __restrict__ w2,
    const float* __restrict__ b2, const float* __restrict__ w3,
    float* __restrict__ rowsum, int M)
{
    __shared__ unsigned short h1s[64 * 256];   // 32 KB, xor-swizzled
    __shared__ unsigned short h0s[64 * 128];   // 16 KB, chunk-XOR swizzled
    const int tid = threadIdx.x;
    const int wave = tid >> 6;
    const int lane = tid & 63;
    const int quad = lane >> 4;
    const int l16 = lane & 15;
    const int bm = blockIdx.x * 64;
    const int nc0 = wave * 64;

    // ---- stage h0 tile: 4 rounds x 256 threads x 16B = 16KB ----
    {
        typedef __attribute__((address_space(1))) const unsigned short* gp_t;
        typedef __attribute__((address_space(3))) unsigned short* lp_t;
#pragma unroll
        for (int p = 0; p < 4; ++p) {
            const int L = p * 256 + tid;
            const int r = L >> 4, sc = L & 15;
            const int c = (sc & 8) | ((sc ^ r) & 7);
            const unsigned short* gsrc = h0 + (size_t)(bm + r) * 128 + c * 8;
            __builtin_amdgcn_global_load_lds((gp_t)gsrc,
                (lp_t)(h0s + (size_t)(p * 256 + wave * 64) * 8), 16, 0, 0);
        }
    }

    f32x4 acc[4][4];
#pragma unroll
    for (int i = 0; i < 4; ++i)
#pragma unroll
        for (int j = 0; j < 4; ++j) {
            f32x4 z = {0.f, 0.f, 0.f, 0.f};
            acc[i][j] = z;
        }

    __syncthreads();   // compiler drains vmcnt before barrier -> tile ready

    // ---- phase 1: h1 = relu(h0 @ W1^T + b1), K=128; A from LDS ----
    {
        const unsigned short* pb[4];
#pragma unroll
        for (int t = 0; t < 4; ++t) {
            int n = nc0 + t * 16 + l16;
            pb[t] = w1 + (size_t)n * 128 + quad * 8;
        }
        short8 af[2][4], bf[2][4];
#pragma unroll
        for (int t = 0; t < 4; ++t) {
            const int row = t * 16 + l16;
            const int c = quad;                       // kt=0
            const int pos = (c & 8) | ((c ^ row) & 7);
            af[0][t] = *reinterpret_cast<const short8*>(&h0s[row * 128 + pos * 8]);
            bf[0][t] = *reinterpret_cast<const short8*>(pb[t]);
        }
#pragma unroll
        for (int kt = 0; kt < 4; ++kt) {
            const int cur = kt & 1, nxt = cur ^ 1;
            if (kt < 3) {
#pragma unroll
                for (int t = 0; t < 4; ++t) {
                    const int row = t * 16 + l16;
                    const int c = (kt + 1) * 4 + quad;
                    const int pos = (c & 8) | ((c ^ row) & 7);
                    af[nxt][t] = *reinterpret_cast<const short8*>(&h0s[row * 128 + pos * 8]);
                    bf[nxt][t] = *reinterpret_cast<const short8*>(pb[t] + (kt + 1) * 32);
                }
            }
#pragma unroll
            for (int i = 0; i < 4; ++i)
#pragma unroll
                for (int j = 0; j < 4; ++j)
                    acc[i][j] = __builtin_amdgcn_mfma_f32_16x16x32_bf16(af[cur][i], bf[cur][j], acc[i][j], 0, 0, 0);
        }
        // relu+bias -> swizzled LDS: (row,col) at row*256 + (((col>>3)^(row&7))<<3 | (col&7))
#pragma unroll
        for (int nt = 0; nt < 4; ++nt) {
            int col = nc0 + nt * 16 + l16;
            float bv = b1[col];
            int chunk = col >> 3, rem = col & 7;
#pragma unroll
            for (int mt = 0; mt < 4; ++mt)
#pragma unroll
                for (int r = 0; r < 4; ++r) {
                    int row = mt * 16 + quad * 4 + r;
                    h1s[row * 256 + (((chunk ^ (row & 7)) << 3) | rem)] =
                        f2b(fmaxf(acc[mt][nt][r] + bv, 0.f));
                }
        }
    }
    __syncthreads();

    // ---- phase 2: h2 = relu(h1s @ W2^T + b2), K=256, ring-3 both streams ----
#pragma unroll
    for (int i = 0; i < 4; ++i)
#pragma unroll
        for (int j = 0; j < 4; ++j) {
            f32x4 z = {0.f, 0.f, 0.f, 0.f};
            acc[i][j] = z;
        }
    {
        const unsigned short* pb[4];
#pragma unroll
        for (int t = 0; t < 4; ++t) {
            int n = nc0 + t * 16 + l16;
            pb[t] = w2 + (size_t)n * 256 + quad * 8;
        }
        short8 af[3][4], bf[3][4];
#pragma unroll
        for (int t = 0; t < 4; ++t) {
            int row = t * 16 + l16;
            af[0][t] = *reinterpret_cast<const short8*>(
                &h1s[row * 256 + ((quad ^ (row & 7)) << 3)]);
            af[1][t] = *reinterpret_cast<const short8*>(
                &h1s[row * 256 + (((4 + quad) ^ (row & 7)) << 3)]);
            bf[0][t] = *reinterpret_cast<const short8*>(pb[t]);
            bf[1][t] = *reinterpret_cast<const short8*>(pb[t] + 32);
        }
#pragma unroll
        for (int kt = 0; kt < 8; ++kt) {
            const int cu = kt % 3, nx = (kt + 2) % 3;
            if (kt + 2 < 8) {
                const int c2 = (kt + 2) * 4 + quad;
#pragma unroll
                for (int t = 0; t < 4; ++t) {
                    int row = t * 16 + l16;
                    af[nx][t] = *reinterpret_cast<const short8*>(
                        &h1s[row * 256 + ((c2 ^ (row & 7)) << 3)]);
                    bf[nx][t] = *reinterpret_cast<const short8*>(pb[t] + (kt + 2) * 32);
                }
            }
#pragma unroll
            for (int i = 0; i < 4; ++i)
#pragma unroll
                for (int j = 0; j < 4; ++j)
                    acc[i][j] = __builtin_amdgcn_mfma_f32_16x16x32_bf16(af[cu][i], bf[cu][j], acc[i][j], 0, 0, 0);
        }
    }

    // ---- fused epilogue: partial w3-dot over this wave's 64 cols ----
    float part[4][4];
#pragma unroll
    for (int mt = 0; mt < 4; ++mt)
#pragma unroll
        for (int r = 0; r < 4; ++r) part[mt][r] = 0.f;
#pragma unroll
    for (int nt = 0; nt < 4; ++nt) {
        int col = nc0 + nt * 16 + l16;
        float bs = b2[col];
        float wv3 = w3[col];
#pragma unroll
        for (int mt = 0; mt < 4; ++mt)
#pragma unroll
            for (int r = 0; r < 4; ++r)
                part[mt][r] += fmaxf(acc[mt][nt][r] + bs, 0.f) * wv3;
    }
#pragma unroll
    for (int mt = 0; mt < 4; ++mt)
#pragma unroll
        for (int r = 0; r < 4; ++r) {
            float v = part[mt][r];
            v += __shfl_xor(v, 1, 64);
            v += __shfl_xor(v, 2, 64);
            v += __shfl_xor(v, 4, 64);
            v += __shfl_xor(v, 8, 64);
            part[mt][r] = v;
        }
    if (l16 == 0) {
#pragma unroll
        for (int mt = 0; mt < 4; ++mt)
#pragma unroll
            for (int r = 0; r < 4; ++r) {
                int row = bm + mt * 16 + quad * 4 + r;
                if (row < M) rowsum[(size_t)row * 4 + wave] = part[mt][r];
            }
    }
}

// ---------------- final: out[g] = b3 + sum of 80 rowsum slots ----------------

__global__ __launch_bounds__(256) void final_k(
    const float* __restrict__ rowsum, const float* __restrict__ b3,
    float* __restrict__ out)
{
    int g = blockIdx.x * 256 + threadIdx.x;
    if (g >= NGRAPH) return;
    const float4* p = reinterpret_cast<const float4*>(rowsum + (size_t)g * 80);
    float s = 0.f;
#pragma unroll
    for (int i = 0; i < 20; ++i) {
        float4 v = p[i];
        s += (v.x + v.y) + (v.z + v.w);
    }
    out[g] = s + b3[0];
}

// ---------------- launch ----------------

extern "C" void kernel_launch(void* const* d_in, const int* in_sizes, int n_in,
                              void* d_out, int out_size, void* d_ws, size_t ws_size,
                              hipStream_t stream)
{
    const float* x      = (const float*)d_in[0];
    const int*   ei     = (const int*)  d_in[1];
    const float* conv_w = (const float*)d_in[2];
    const float* conv_b = (const float*)d_in[3];
    const float* lin1_w = (const float*)d_in[4];
    const float* lin1_b = (const float*)d_in[5];
    const float* lin2_w = (const float*)d_in[6];
    const float* lin2_b = (const float*)d_in[7];
    const float* lin3_w = (const float*)d_in[8];
    const float* lin3_b = (const float*)d_in[9];
    float* out = (float*)d_out;

    // Workspace (~80 MB):
    //   xws bf16 [(N+8)*128] | h0 bf16 [N*128] (doubles as xbf before gather)
    //   entries | csr | rowptr2 int2 [N] | dinv [N] | bfill [NB]
    //   wt0/wt1/wt2 | rowsum [100096*4]
    unsigned short* xws     = (unsigned short*)d_ws;
    unsigned short* h0      = xws + (size_t)(NNODES + 8) * 128;   // aka xbf
    unsigned*       entries = (unsigned*)(h0 + (size_t)NNODES * 128);
    int*            csr     = (int*)(entries + (size_t)NB * CAP);
    int2*           rowptr2 = (int2*)(csr + (size_t)NB * CAP);
    float*          dinv    = (float*)(rowptr2 + NNODES);
    int*            bfill   = (int*)(dinv + NNODES);
    unsigned short* wt0     = (unsigned short*)(bfill + NB + 8);
    unsigned short* wt1     = wt0 + 16384;
    unsigned short* wt2     = wt1 + 32768;
    float*          rowsum  = (float*)(wt2 + 65536);

    // CSR build + folded weight conversions + x->bf16 (into h0 buffer)
    hipMemsetAsync(bfill, 0, NB * sizeof(int), stream);
    bin_k<<<BIN_WGS + CVT_WGS, 256, 0, stream>>>(ei, bfill, entries,
                                                 conv_w, lin1_w, lin2_w, x,
                                                 wt0, wt1, wt2, h0);
    bucket_build_k<<<NB, 256, 0, stream>>>(entries, bfill, rowptr2, csr, dinv);

    // gemm0: xws = (xbf @ conv_w) * dinv[row]; A staged via global_load_lds
    mgemm0_k<<<(NNODES + 127) / 128, 256, 0, stream>>>(h0, wt0, dinv, xws, NNODES);

    // gather + conv epilogue + residual (fp32 x) -> h0 row-major (overwrites xbf)
    gather_k<<<(NNODES + 3) / 4, 256, 0, stream>>>(rowptr2, csr, xws, dinv, x, conv_b, h0);

    // fused MLP: stage h0 -> gemm1 -> LDS -> gemm2 -> w3-dot -> rowsum
    fmlp_k<<<(NNODES + 63) / 64, 256, 0, stream>>>(h0, wt1, lin1_b, wt2, lin2_b, lin3_w,
                                                   rowsum, NNODES);

    // out[g] = b3 + sum of this graph's 80 rowsum slots
    final_k<<<(NGRAPH + 255) / 256, 256, 0, stream>>>(rowsum, lin3_b, out);
}